// Round 11
// baseline (346.497 us; speedup 1.0000x reference)
//
#include <hip/hip_runtime.h>
#include <hip/hip_bf16.h>
#include <cstdint>

typedef short short8 __attribute__((ext_vector_type(8)));
typedef float floatx4 __attribute__((ext_vector_type(4)));
typedef unsigned short ushortx4 __attribute__((ext_vector_type(4)));
typedef unsigned int uintx4 __attribute__((ext_vector_type(4)));

#define MFMA16B(A, B, C) __builtin_amdgcn_mfma_f32_16x16x32_bf16((A), (B), (C), 0, 0, 0)
#define LDS_FENCE() asm volatile("" ::: "memory")

__device__ __forceinline__ unsigned short f2bf(float f) {
  union { float f; unsigned u; } v; v.f = f;
  unsigned r = v.u + 0x7FFFu + ((v.u >> 16) & 1u);
  return (unsigned short)(r >> 16);
}
__device__ __forceinline__ unsigned pack_bf2(float a, float b) {
  __hip_bfloat162 h = __float22bfloat162_rn(float2{a, b});
  union { __hip_bfloat162 h; unsigned u; } c; c.h = h; return c.u;
}
__device__ __forceinline__ float lo_half_f(unsigned u) {
  union { unsigned u; float f; } c; c.u = u << 16; return c.f;
}
__device__ __forceinline__ float hi_half_f(unsigned u) {
  union { unsigned u; float f; } c; c.u = u & 0xffff0000u; return c.f;
}
__device__ __forceinline__ ushortx4 pack_bf4(float a, float b, float c, float d) {
  uint2 p; p.x = pack_bf2(a, b); p.y = pack_bf2(c, d);
  union { uint2 u; ushortx4 s; } v; v.u = p; return v.s;
}

__global__ void __launch_bounds__(256) prep_weights(const float* __restrict__ wq,
                                                    const float* __restrict__ wp,
                                                    unsigned short* __restrict__ wq_h,
                                                    unsigned short* __restrict__ wp_h) {
  int i = blockIdx.x * 256 + threadIdx.x;
  if (i < 384 * 128) wq_h[i] = f2bf(wq[i]);
  if (i < 128 * 128) wp_h[i] = f2bf(wp[i]);
}

// One block = one window; wave = one head end-to-end. LDS 48KB (3 blocks/CU):
//   X [64][512B hi|lo] at 0-32K (dies at 1st barrier)
//   per-wave Q[64][64B]|K at wv*8192 (aliases X; later P[64][128B])
//   per-wave V^T[32][128B] at 32768+wv*4096 (never aliases X -> direct store)
//   Os [64][272B] at 0 after 2nd barrier
__global__ void __launch_bounds__(256, 3) win_attn(const float* __restrict__ x,
                                                   const unsigned short* __restrict__ wqh,
                                                   const unsigned short* __restrict__ wph,
                                                   const float* __restrict__ bias,
                                                   float* __restrict__ out) {
  __shared__ char smem[49152];
  const int tid = threadIdx.x;
  const int wv = tid >> 6, lane = tid & 63, lr = lane & 15, lg = lane >> 4;
  const int bid = blockIdx.x;
  const int b = bid >> 6, g = bid & 63, gh = g >> 3, gw = g & 7;
  const size_t base = (size_t)b * (4096 * 128);

  // ---- phase 0: stage X window once per block (hi/lo bf16, packed converts) ----
  {
    const int r = tid >> 2, c0 = (tid & 3) * 32;
    const int n = gh * 512 + (r >> 3) * 64 + gw * 8 + (r & 7);
    const float4* xp = (const float4*)(x + base + (size_t)n * 128 + c0);
    const int rb = r * 512, sz = (r & 7) << 4;
#pragma unroll
    for (int i = 0; i < 4; ++i) {
      float4 u = xp[2 * i], w = xp[2 * i + 1];
      unsigned h0 = pack_bf2(u.x, u.y), h1 = pack_bf2(u.z, u.w);
      unsigned h2 = pack_bf2(w.x, w.y), h3 = pack_bf2(w.z, w.w);
      unsigned l0 = pack_bf2(u.x - lo_half_f(h0), u.y - hi_half_f(h0));
      unsigned l1 = pack_bf2(u.z - lo_half_f(h1), u.w - hi_half_f(h1));
      unsigned l2 = pack_bf2(w.x - lo_half_f(h2), w.y - hi_half_f(h2));
      unsigned l3 = pack_bf2(w.z - lo_half_f(h3), w.w - hi_half_f(h3));
      uintx4 hv = {h0, h1, h2, h3}, lv = {l0, l1, l2, l3};
      *(uintx4*)(smem + ((rb + (c0 + 8 * i) * 2) ^ sz)) = hv;
      *(uintx4*)(smem + ((rb + 256 + (c0 + 8 * i) * 2) ^ sz)) = lv;
    }
  }
  __syncthreads();

  const int swzx = (lr & 7) << 4;
  const float SCALE = 0.17677669529663687f;  // 32^-0.5, folded into Q

  char* const qkbase = smem + wv * 8192;           // Q | K, later P
  char* const vbase  = smem + 32768 + wv * 4096;   // V^T (no X alias)

  // ---- phase 1: QKV; Q/K -> 16 packed regs, V -> LDS directly ----
  ushortx4 pk[4][4];
#pragma unroll
  for (int j = 0; j < 6; ++j) {  // Q0 Q1 K0 K1 V0 V1
    const int jt = j & 1;
    const unsigned short* wb =
        wqh + (size_t)((j >> 1) * 128 + wv * 32 + jt * 16 + lr) * 128 + lg * 8;
    short8 bw0 = *(const short8*)(wb);
    short8 bw1 = *(const short8*)(wb + 32);
    short8 bw2 = *(const short8*)(wb + 64);
    short8 bw3 = *(const short8*)(wb + 96);
    const float fs = (j < 2) ? SCALE : 1.0f;
#pragma unroll
    for (int mt = 0; mt < 4; ++mt) {
      const int rbase = (16 * mt + lr) * 512 + lg * 16;
      floatx4 aH = {0.f, 0.f, 0.f, 0.f}, aL = {0.f, 0.f, 0.f, 0.f};
      aH = MFMA16B(*(const short8*)(smem + ((rbase) ^ swzx)), bw0, aH);
      aH = MFMA16B(*(const short8*)(smem + ((rbase + 64) ^ swzx)), bw1, aH);
      aH = MFMA16B(*(const short8*)(smem + ((rbase + 128) ^ swzx)), bw2, aH);
      aH = MFMA16B(*(const short8*)(smem + ((rbase + 192) ^ swzx)), bw3, aH);
      aL = MFMA16B(*(const short8*)(smem + ((rbase + 256) ^ swzx)), bw0, aL);
      aL = MFMA16B(*(const short8*)(smem + ((rbase + 320) ^ swzx)), bw1, aL);
      aL = MFMA16B(*(const short8*)(smem + ((rbase + 384) ^ swzx)), bw2, aL);
      aL = MFMA16B(*(const short8*)(smem + ((rbase + 448) ^ swzx)), bw3, aL);
      floatx4 acc = aH + aL;
      if (j < 4) {
        pk[j][mt] = pack_bf4(acc[0] * fs, acc[1] * fs, acc[2] * fs, acc[3] * fs);
      } else {
        const int d = jt * 16 + lr;
        *(ushortx4*)(vbase + ((d * 128 + (16 * mt + 4 * lg) * 2) ^ ((d & 7) << 4))) =
            pack_bf4(acc[0], acc[1], acc[2], acc[3]);
      }
    }
  }
  __syncthreads();  // X dead; Q/K region writable

  // ---- phase 1b: spill Q/K; swizzle (s&7)<<4 (bit6 swaps row pairs; bijective) ----
#pragma unroll
  for (int j = 0; j < 4; ++j) {
    char* qk = qkbase + (j >> 1) * 4096;
    const int d = (j & 1) * 16 + lr;
#pragma unroll
    for (int mt = 0; mt < 4; ++mt)
#pragma unroll
      for (int r = 0; r < 4; ++r) {
        const int s = 16 * mt + 4 * lg + r;
        *(unsigned short*)(qk + ((s * 64 + d * 2) ^ ((s & 7) << 4))) = pk[j][mt][r];
      }
  }
  LDS_FENCE();

  // ---- phase 2: per s-column-group: QK^T MFMA -> softmax -> P store ----
  const int swzp = (lr & 7) << 4;  // row&7 == lr&7 for all tiles here
  short8 ka[4];
#pragma unroll
  for (int i = 0; i < 4; ++i)
    ka[i] = *(const short8*)(qkbase + 4096 + (((16 * i + lr) * 64 + lg * 16) ^ swzp));
  short8 qb0 = *(const short8*)(qkbase + (((lr) * 64 + lg * 16) ^ swzp));
  short8 qb1 = *(const short8*)(qkbase + (((16 + lr) * 64 + lg * 16) ^ swzp));
  short8 qb2 = *(const short8*)(qkbase + (((32 + lr) * 64 + lg * 16) ^ swzp));
  short8 qb3 = *(const short8*)(qkbase + (((48 + lr) * 64 + lg * 16) ^ swzp));
  LDS_FENCE();  // all Q/K frags in regs before P overwrites

  auto softcol = [&](int nt, short8 qbv) {
    floatx4 sc4[4];
#pragma unroll
    for (int mt = 0; mt < 4; ++mt) {
      floatx4 z = {0.f, 0.f, 0.f, 0.f};
      sc4[mt] = MFMA16B(ka[mt], qbv, z);  // t = 16mt+4lg+r, s = 16nt+lr
    }
    float m0 = -1e30f;
#pragma unroll
    for (int mt = 0; mt < 4; ++mt)
#pragma unroll
      for (int r = 0; r < 4; ++r) m0 = fmaxf(m0, sc4[mt][r]);
    m0 = fmaxf(m0, __shfl_xor(m0, 16));
    m0 = fmaxf(m0, __shfl_xor(m0, 32));
    float s0 = 0.f;
#pragma unroll
    for (int mt = 0; mt < 4; ++mt)
#pragma unroll
      for (int r = 0; r < 4; ++r) {
        float e = __expf(sc4[mt][r] - m0);
        sc4[mt][r] = e;
        s0 += e;
      }
    s0 += __shfl_xor(s0, 16);
    s0 += __shfl_xor(s0, 32);
    const float inv = 1.f / s0;
    const int rb = (16 * nt + lr) * 128;
#pragma unroll
    for (int mt = 0; mt < 4; ++mt)
      *(ushortx4*)(qkbase + ((rb + (16 * mt + 4 * lg) * 2) ^ swzp)) =
          pack_bf4(sc4[mt][0] * inv, sc4[mt][1] * inv, sc4[mt][2] * inv,
                   sc4[mt][3] * inv);
    LDS_FENCE();
  };
  softcol(0, qb0);
  softcol(1, qb1);
  softcol(2, qb2);
  softcol(3, qb3);

  // ---- phase 3: O^T[d][s] = V^T · P^T (st-outer; 2 P-frags live) ----
  short8 va00 = *(const short8*)(vbase + (((lr) * 128 + lg * 16) ^ swzp));
  short8 va01 = *(const short8*)(vbase + (((lr) * 128 + 64 + lg * 16) ^ swzp));
  short8 va10 = *(const short8*)(vbase + (((16 + lr) * 128 + lg * 16) ^ swzp));
  short8 va11 = *(const short8*)(vbase + (((16 + lr) * 128 + 64 + lg * 16) ^ swzp));
  floatx4 ot[2][4];
#pragma unroll
  for (int st = 0; st < 4; ++st) {
    const int pr = (16 * st + lr) * 128;
    short8 pb0 = *(const short8*)(qkbase + ((pr + lg * 16) ^ swzp));
    short8 pb1 = *(const short8*)(qkbase + ((pr + 64 + lg * 16) ^ swzp));
    floatx4 z0 = {0.f, 0.f, 0.f, 0.f};
    floatx4 t0 = MFMA16B(va00, pb0, z0);
    ot[0][st] = MFMA16B(va01, pb1, t0);
    floatx4 z1 = {0.f, 0.f, 0.f, 0.f};
    floatx4 t1 = MFMA16B(va10, pb0, z1);
    ot[1][st] = MFMA16B(va11, pb1, t1);
  }

  __syncthreads();  // per-wave regions dead before Os overwrites

  // ---- Os[s][32wv+d], pitch 272B ----
#pragma unroll
  for (int st = 0; st < 4; ++st)
#pragma unroll
    for (int dt = 0; dt < 2; ++dt)
      *(ushortx4*)(smem + (16 * st + lr) * 272 + (wv * 32 + dt * 16 + 4 * lg) * 2) =
          pack_bf4(ot[dt][st][0], ot[dt][st][1], ot[dt][st][2], ot[dt][st][3]);
  __syncthreads();

  // ---- phase 4: out-proj, wave wv owns token rows 16wv..+15 ----
  short8 ao0 = *(const short8*)(smem + (16 * wv + lr) * 272 + lg * 16);
  short8 ao1 = *(const short8*)(smem + (16 * wv + lr) * 272 + 64 + lg * 16);
  short8 ao2 = *(const short8*)(smem + (16 * wv + lr) * 272 + 128 + lg * 16);
  short8 ao3 = *(const short8*)(smem + (16 * wv + lr) * 272 + 192 + lg * 16);
#pragma unroll
  for (int nt = 0; nt < 8; ++nt) {
    const unsigned short* wb = wph + (size_t)(nt * 16 + lr) * 128 + lg * 8;
    floatx4 acc = {0.f, 0.f, 0.f, 0.f};
    acc = MFMA16B(ao0, *(const short8*)(wb), acc);
    acc = MFMA16B(ao1, *(const short8*)(wb + 32), acc);
    acc = MFMA16B(ao2, *(const short8*)(wb + 64), acc);
    acc = MFMA16B(ao3, *(const short8*)(wb + 96), acc);
    const float bb = bias[nt * 16 + lr];
#pragma unroll
    for (int r = 0; r < 4; ++r) {
      const int s0 = 16 * wv + 4 * lg + r;
      const int n = gh * 512 + (s0 >> 3) * 64 + gw * 8 + (s0 & 7);
      out[base + (size_t)n * 128 + nt * 16 + lr] = acc[r] + bb;
    }
  }
}

extern "C" void kernel_launch(void* const* d_in, const int* in_sizes, int n_in,
                              void* d_out, int out_size, void* d_ws, size_t ws_size,
                              hipStream_t stream) {
  (void)in_sizes; (void)n_in; (void)out_size; (void)ws_size;
  const float* x  = (const float*)d_in[0];
  const float* wq = (const float*)d_in[1];
  const float* wp = (const float*)d_in[2];
  const float* bp = (const float*)d_in[3];
  float* out = (float*)d_out;
  unsigned short* wq_h = (unsigned short*)d_ws;   // 384*128 bf16
  unsigned short* wp_h = wq_h + 384 * 128;        // 128*128 bf16
  prep_weights<<<192, 256, 0, stream>>>(wq, wp, wq_h, wp_h);
  win_attn<<<2048, 256, 0, stream>>>(x, wq_h, wp_h, bp, out);
}